// Round 9
// baseline (851.753 us; speedup 1.0000x reference)
//
#include <hip/hip_runtime.h>
#include <stdint.h>

#define NTAGS 512
#define STAG 510
#define PTAG 511
#define SEQ 512
#define L2E 1.4426950408889634f
#define LN2 0.6931471805599453f
#define MARGIN 13

typedef int   v8i __attribute__((ext_vector_type(8)));
typedef float v4f __attribute__((ext_vector_type(4)));

// fast 2^x: raw v_exp_f32 (OCML exp2f is a ~25-instr libcall)
__device__ __forceinline__ float fexp2(float x) {
#if __has_builtin(__builtin_amdgcn_exp2f)
    return __builtin_amdgcn_exp2f(x);
#else
    float r; asm("v_exp_f32 %0, %1\n\ts_nop 1" : "=v"(r) : "v"(x)); return r;
#endif
}

// max with a DPP-permuted copy (ctrl must be a literal)
#define DPPMAX(X, CTRL) fmaxf((X), __int_as_float(__builtin_amdgcn_update_dpp( \
    0, __float_as_int(X), (CTRL), 0xF, 0xF, false)))
// 0xB1 = quad_perm xor1 ; 0x4E = quad_perm xor2 ; 0x141 = row_half_mirror (xor7) ; 0x140 = row_mirror (xor15)

// raw barrier: order LDS only; leave VMEM (em prefetch) in flight across it
#define STEP_SYNC() asm volatile("s_waitcnt lgkmcnt(0)\n\ts_barrier" ::: "memory")

// ws layout: E6 fp6 blocks 512*16*24B = 196608 | scales 8192 | part 512B
#define WS_SC   196608
#define WS_PART 204800

// ---------------- setup: E = exp(trans) -> MX-fp6 e2m3, k-permuted (4-wave pi), packed ----
// pi for the 4-wave producer: byte position p (0..511): d=p>>2, q=p&3,
//   w=d>>5, h=(d>>4)&1, c=d&15  ->  source prev-tag = w*128 + (h*4+q)*16 + c.
// With p = KB*32 + k:  n_src = (KB>>2)*128 + (((KB>>1)&1)*4 + (k&3))*16 + (KB&1)*8 + (k>>2).
__global__ void crf_setup_k(const float* __restrict__ trans, uint8_t* __restrict__ ws)
{
    int t = blockIdx.x * blockDim.x + threadIdx.x;   // 8192 threads
    int n = t >> 4, KB = t & 15;
    const float* row = trans + n * NTAGS;
    float v[32]; float mx = -3.0e38f;
    #pragma unroll
    for (int k = 0; k < 32; ++k) {
        int p = (KB>>2)*128 + (((KB>>1)&1)*4 + (k&3))*16 + (KB&1)*8 + (k>>2);
        v[k] = row[p]; mx = fmaxf(mx, v[k]);
    }
    int e = (int)floorf(mx * L2E - 2.90689059f);     // blockmax -> (3.75, 7.5]
    int byt = e + 127; byt = byt < 0 ? 0 : (byt > 254 ? 254 : byt);
    float eeff = (float)(byt - 127);
    uint32_t out[6] = {0u,0u,0u,0u,0u,0u};
    #pragma unroll
    for (int k = 0; k < 32; ++k) {
        float q = exp2f(v[k] * L2E - eeff);          // in [0, 7.5]
        int code;
        if      (q < 2.0f) code = (int)(q * 8.0f + 0.5f);
        else if (q < 4.0f) code = 16 + (int)((q - 2.0f) * 4.0f + 0.5f);
        else               code = 24 + (int)((q - 4.0f) * 2.0f + 0.5f);
        code = code > 31 ? 31 : code;
        int bp = 6*k, d = bp >> 5, off = bp & 31;
        out[d] |= (uint32_t)code << off;
        if (off > 26) out[d+1] |= (uint32_t)code >> (32 - off);
    }
    uint32_t* E6 = (uint32_t*)ws;
    int base = (n*16 + KB) * 6;
    #pragma unroll
    for (int d = 0; d < 6; ++d) E6[base + d] = out[d];
    ws[WS_SC + n*16 + (KB & 3)*4 + (KB >> 2)] = (uint8_t)byt;
}

// ---------------- main: 8 WGs x 16 batches, 256 threads (4 waves, 1 wave/SIMD) ----------------
__global__ __launch_bounds__(256, 1) void crf_main_k(
    const float* __restrict__ inp, const float* __restrict__ trans,
    const uint8_t* __restrict__ ws, float* __restrict__ part)
{
    __shared__ uint8_t aqb[2*8192];
    __shared__ int     mxp[2*16];
    __shared__ float   mxb[16*4];
    __shared__ float   ssum[16*4];
    __shared__ float   Gb[16];

    const int tid = threadIdx.x;
    const int w = tid >> 6, l = tid & 63, c = l & 15, g = l >> 4;
    const int wg = blockIdx.x;
    const int b0 = g * 4;
    const int SCA = 0x78787878;   // constant A-scale: e8m0 120 = 2^-7, all blocks

    // ---- persistent B fragments: 8 n-tiles x 4 k-blocks, fp6, pinned into AGPRs ----
    v8i Bf[32];
    int esc[8];
    #pragma unroll
    for (int i = 0; i < 8; ++i) {
        const int n = (w*8 + i)*16 + c;
        esc[i] = *(const int*)(ws + WS_SC + n*16 + g*4);
        #pragma unroll
        for (int kk = 0; kk < 4; ++kk) {
            const uint2* p2 = (const uint2*)((const uint32_t*)ws + (n*16 + kk*4 + g)*6);
            uint2 d0 = p2[0], d1 = p2[1], d2 = p2[2];
            v8i bv;
            bv[0]=(int)d0.x; bv[1]=(int)d0.y; bv[2]=(int)d1.x;
            bv[3]=(int)d1.y; bv[4]=(int)d2.x; bv[5]=(int)d2.y;
            bv[6]=0; bv[7]=0;
            Bf[i*4 + kk] = bv;
        }
    }
    // Pin Bf into the AGPR file (32 x 8 = 256 AGPRs, otherwise idle at 1 wave/SIMD);
    // prevents spill (R3) and loop re-load (R4). esc stays in VGPRs.
    #pragma unroll
    for (int i = 0; i < 32; ++i) asm volatile("" : "+a"(Bf[i]));
    #pragma unroll
    for (int i = 0; i < 8; ++i)  asm volatile("" : "+v"(esc[i]));

    const float* ep[4];
    #pragma unroll
    for (int j = 0; j < 4; ++j)
        ep[j] = inp + (size_t)(wg*16 + b0 + j) * (SEQ*NTAGS) + w*128 + c;   // row 0

    // producer store indices: batch bb, halves h=0 (i0..3) / h=1 (i4..7)
    int aqoff0[4], aqoff1[4];
    #pragma unroll
    for (int j = 0; j < 4; ++j) {
        int bb = b0 + j;
        aqoff0[j] = bb*128 + (((w*8 + 0 + (c>>2)) ^ (bb & 7)) << 2) + (c & 3);
        aqoff1[j] = bb*128 + (((w*8 + 4 + (c>>2)) ^ (bb & 7)) << 2) + (c & 3);
    }
    // consumer A-fragment offsets (16B units), row = batch = c
    int aoffA[8];
    #pragma unroll
    for (int kk = 0; kk < 4; ++kk) {
        aoffA[2*kk]   = c*32 + ((kk*8 + g*2)     ^ (c & 7));
        aoffA[2*kk+1] = c*32 + ((kk*8 + g*2 + 1) ^ (c & 7));
    }

    // ---- init: alpha_1[n] = inp[b,0,n] + trans[n,STAG]; exact max; fp8 store ----
    float vv[4][8];
    {
        float tr[8];
        #pragma unroll
        for (int i = 0; i < 8; ++i) tr[i] = trans[(w*128 + i*16 + c)*NTAGS + STAG];
        #pragma unroll
        for (int j = 0; j < 4; ++j) {
            #pragma unroll
            for (int i = 0; i < 8; ++i)
                vv[j][i] = ep[j][i*16] + tr[i];
        }
    }
    float Mj[4];
    #pragma unroll
    for (int j = 0; j < 4; ++j) {
        float m = -3.0e38f;
        #pragma unroll
        for (int i = 0; i < 8; ++i) m = fmaxf(m, vv[j][i]);
        #pragma unroll
        for (int msk = 1; msk <= 8; msk <<= 1) m = fmaxf(m, __shfl_xor(m, msk, 64));
        if (c == 0) mxb[(b0 + j)*4 + w] = m;
    }
    __syncthreads();
    float G[4];
    #pragma unroll
    for (int j = 0; j < 4; ++j) {
        float m = -3.0e38f;
        #pragma unroll
        for (int k = 0; k < 4; ++k) m = fmaxf(m, mxb[(b0 + j)*4 + k]);
        Mj[j] = m;
        G[j] = m * L2E;
    }
    {
        uint32_t* AQ = (uint32_t*)(aqb + 8192);   // buffer 1 (s=1 reads cur=1)
        #pragma unroll
        for (int j = 0; j < 4; ++j) {
            float q[8];
            #pragma unroll
            for (int i = 0; i < 8; ++i) q[i] = fexp2((vv[j][i] - Mj[j]) * L2E + 7.0f);
            int t0 = __builtin_amdgcn_cvt_pk_fp8_f32(q[0], q[1], 0, false);
            t0 = __builtin_amdgcn_cvt_pk_fp8_f32(q[2], q[3], t0, true);
            int t1 = __builtin_amdgcn_cvt_pk_fp8_f32(q[4], q[5], 0, false);
            t1 = __builtin_amdgcn_cvt_pk_fp8_f32(q[6], q[7], t1, true);
            AQ[aqoff0[j]] = (uint32_t)t0;
            AQ[aqoff1[j]] = (uint32_t)t1;
        }
    }
    if (w == 0 && c == 0) { int4 z; z.x=0; z.y=0; z.z=0; z.w=0; *(int4*)&mxp[16 + g*4] = z; }

    // prologue: advance ep to row 1, prefetch raw em(s=1)
    float emn[4][8];
    #pragma unroll
    for (int j = 0; j < 4; ++j) ep[j] += NTAGS;
    #pragma unroll
    for (int j = 0; j < 4; ++j) {
        #pragma unroll
        for (int i = 0; i < 8; ++i) emn[j][i] = ep[j][i*16];
    }
    __syncthreads();

#define MFMA_K(KK) do { \
    v8i A_; \
    *(int4*)&A_       = Areg[2*(KK)]; \
    *(((int4*)&A_)+1) = Areg[2*(KK)+1]; \
    _Pragma("unroll") \
    for (int i = 0; i < 8; ++i) \
        D[i] = __builtin_amdgcn_mfma_scale_f32_16x16x128_f8f6f4(A_, Bf[i*4+(KK)], D[i], 0, 2, (KK), SCA, (KK), esc[i]); \
} while (0)

    for (int s = 1; s < SEQ; ++s) {
        const int cur = s & 1, nxt = cur ^ 1;

        // hoisted LDS reads: stale-max + full A fragment set (latency hides under emx)
        int4 Pv = *(const int4*)&mxp[cur*16 + g*4];
        const int4* aq4 = (const int4*)(aqb + cur*8192);
        int4 Areg[8];
        #pragma unroll
        for (int t = 0; t < 8; ++t) Areg[t] = aq4[aoffA[t]];

        int Rj[4]; float dmj[4];
        #pragma unroll
        for (int j = 0; j < 4; ++j) {
            Rj[j] = ((const int*)&Pv)[j] + MARGIN;
            dmj[j] = (float)(7 - Rj[j]);
        }
        // folded emission factors (raw em prefetched last step, already resident)
        float emx[4][8];
        #pragma unroll
        for (int j = 0; j < 4; ++j) {
            #pragma unroll
            for (int i = 0; i < 8; ++i)
                emx[j][i] = fexp2(fmaf(emn[j][i], L2E, dmj[j]));
        }
        // prefetch raw em for NEXT step (survives the raw barrier; drains at next use)
        if (s < SEQ - 1) {
            #pragma unroll
            for (int j = 0; j < 4; ++j) ep[j] += NTAGS;
            #pragma unroll
            for (int j = 0; j < 4; ++j) {
                #pragma unroll
                for (int i = 0; i < 8; ++i) emn[j][i] = ep[j][i*16];
            }
        }

        v4f D[8];
        #pragma unroll
        for (int i = 0; i < 8; ++i) { D[i][0]=0.f; D[i][1]=0.f; D[i][2]=0.f; D[i][3]=0.f; }
        __builtin_amdgcn_s_setprio(1);
        MFMA_K(0); MFMA_K(1); MFMA_K(2); MFMA_K(3);
        __builtin_amdgcn_s_setprio(0);

        if (s < SEQ - 1) {
            #pragma unroll
            for (int j = 0; j < 4; ++j) G[j] += (float)Rj[j];

            // quantize (fold already in emx). fminf(448) is REQUIRED: the fp8 cvt
            // has no clamp here -- overflow yields NaN (the R8 failure), and vq
            // exceeds 448 whenever this step's growth beats the stale estimate.
            float vq[4][8];
            #pragma unroll
            for (int j = 0; j < 4; ++j) {
                #pragma unroll
                for (int i = 0; i < 8; ++i)
                    vq[j][i] = fminf(D[i][j] * emx[j][i], 448.0f);
            }
            uint32_t* AQ = (uint32_t*)(aqb + nxt*8192);
            #pragma unroll
            for (int j = 0; j < 4; ++j) {
                int t0 = __builtin_amdgcn_cvt_pk_fp8_f32(vq[j][0], vq[j][1], 0, false);
                t0 = __builtin_amdgcn_cvt_pk_fp8_f32(vq[j][2], vq[j][3], t0, true);
                int t1 = __builtin_amdgcn_cvt_pk_fp8_f32(vq[j][4], vq[j][5], 0, false);
                t1 = __builtin_amdgcn_cvt_pk_fp8_f32(vq[j][6], vq[j][7], t1, true);
                AQ[aqoff0[j]] = (uint32_t)t0;
                AQ[aqoff1[j]] = (uint32_t)t1;
            }
            if (w == 0) {   // wave-uniform: stale-max post only on wave 0 (128-n sample)
                int4 post;
                #pragma unroll
                for (int j = 0; j < 4; ++j) {
                    float bm = -3.0e38f;
                    #pragma unroll
                    for (int i = 0; i < 8; ++i) bm = fmaxf(bm, vq[j][i]);
                    bm = DPPMAX(bm, 0xB1); bm = DPPMAX(bm, 0x4E);
                    bm = DPPMAX(bm, 0x141); bm = DPPMAX(bm, 0x140);
                    int be = (int)((__float_as_uint(bm) >> 23) & 255u) - 127;
                    be = be < -30 ? -30 : be;
                    ((int*)&post)[j] = be - 7;   // == exp(unfolded v-max) - Rj
                }
                if (c == 0) *(int4*)&mxp[nxt*16 + g*4] = post;
            }
            STEP_SYNC();
        } else {
            // ---- final: loss_b = LN2*(G + max_x + log2 sum 2^(x - max)); emn holds raw em(511) ----
            float ts[8];
            #pragma unroll
            for (int i = 0; i < 8; ++i) ts[i] = trans[PTAG*NTAGS + w*128 + i*16 + c];
            float x[4][8];
            #pragma unroll
            for (int j = 0; j < 4; ++j) {
                #pragma unroll
                for (int i = 0; i < 8; ++i)
                    x[j][i] = __log2f(D[i][j]) + (emn[j][i] + ts[i]) * L2E;
            }
            #pragma unroll
            for (int j = 0; j < 4; ++j) {
                float m = -3.0e38f;
                #pragma unroll
                for (int i = 0; i < 8; ++i) m = fmaxf(m, x[j][i]);
                #pragma unroll
                for (int msk = 1; msk <= 8; msk <<= 1) m = fmaxf(m, __shfl_xor(m, msk, 64));
                if (c == 0) mxb[(b0 + j)*4 + w] = m;
            }
            if (w == 0 && c == 0) {
                #pragma unroll
                for (int j = 0; j < 4; ++j) Gb[b0 + j] = G[j];
            }
            __syncthreads();
            #pragma unroll
            for (int j = 0; j < 4; ++j) {
                float XM = -3.0e38f;
                #pragma unroll
                for (int k = 0; k < 4; ++k) XM = fmaxf(XM, mxb[(b0 + j)*4 + k]);
                float sj = 0.f;
                #pragma unroll
                for (int i = 0; i < 8; ++i) sj += fexp2(x[j][i] - XM);
                #pragma unroll
                for (int msk = 1; msk <= 8; msk <<= 1) sj += __shfl_xor(sj, msk, 64);
                if (c == 0) ssum[(b0 + j)*4 + w] = sj;
            }
            __syncthreads();
            if (tid < 16) {
                float S = 0.f, XM = -3.0e38f;
                #pragma unroll
                for (int k = 0; k < 4; ++k) { S += ssum[tid*4 + k]; XM = fmaxf(XM, mxb[tid*4 + k]); }
                part[wg*16 + tid] = LN2 * (Gb[tid] + XM + __log2f(S));
            }
        }
    }
#undef MFMA_K
}

__global__ void crf_final_k(const float* __restrict__ part, float* __restrict__ out)
{
    int t = threadIdx.x;  // 64
    float vsum = part[t] + part[t + 64];
    #pragma unroll
    for (int off = 32; off; off >>= 1) vsum += __shfl_down(vsum, off, 64);
    if (t == 0) out[0] = vsum;
}

extern "C" void kernel_launch(void* const* d_in, const int* in_sizes, int n_in,
                              void* d_out, int out_size, void* d_ws, size_t ws_size,
                              hipStream_t stream)
{
    (void)in_sizes; (void)n_in; (void)out_size; (void)ws_size;
    const float* inp   = (const float*)d_in[0];
    // d_in[1] = tags: unused (partition function only)
    const float* trans = (const float*)d_in[2];
    uint8_t* ws = (uint8_t*)d_ws;
    float* part = (float*)(ws + WS_PART);

    crf_setup_k<<<64, 128, 0, stream>>>(trans, ws);
    crf_main_k<<<8, 256, 0, stream>>>(inp, trans, ws, part);
    crf_final_k<<<1, 64, 0, stream>>>(part, (float*)d_out);
}

// Round 10
// 734.430 us; speedup vs baseline: 1.1597x; 1.1597x over previous
//
#include <hip/hip_runtime.h>
#include <stdint.h>

#define NTAGS 512
#define STAG 510
#define PTAG 511
#define SEQ 512
#define L2E 1.4426950408889634f
#define LN2 0.6931471805599453f
#define MARGIN 13

typedef int   v8i __attribute__((ext_vector_type(8)));
typedef float v4f __attribute__((ext_vector_type(4)));

// fast 2^x: raw v_exp_f32 (OCML exp2f is a ~25-instr libcall)
__device__ __forceinline__ float fexp2(float x) {
#if __has_builtin(__builtin_amdgcn_exp2f)
    return __builtin_amdgcn_exp2f(x);
#else
    float r; asm("v_exp_f32 %0, %1\n\ts_nop 1" : "=v"(r) : "v"(x)); return r;
#endif
}

// max with a DPP-permuted copy (ctrl must be a literal)
#define DPPMAX(X, CTRL) fmaxf((X), __int_as_float(__builtin_amdgcn_update_dpp( \
    0, __float_as_int(X), (CTRL), 0xF, 0xF, false)))
// 0xB1 = quad_perm xor1 ; 0x4E = quad_perm xor2 ; 0x141 = row_half_mirror (xor7) ; 0x140 = row_mirror (xor15)

// raw barrier: order LDS only; leave VMEM (em prefetch) in flight across it
#define STEP_SYNC() asm volatile("s_waitcnt lgkmcnt(0)\n\ts_barrier" ::: "memory")

// ws layout: E6 fp6 blocks 512*16*24B = 196608 | scales 8192 | part 512B
#define WS_SC   196608
#define WS_PART 204800

// ---------------- setup: E = exp(trans) -> MX-fp6 e2m3, k-permuted, packed 6 dwords ----
// Block (n, KB), KB = kk*4 + g. k-permutation p = (KB>>1)*64 + (idx&3)*16 + (KB&1)*8 + (idx>>2).
__global__ void crf_setup_k(const float* __restrict__ trans, uint8_t* __restrict__ ws)
{
    int t = blockIdx.x * blockDim.x + threadIdx.x;   // 8192 threads
    int n = t >> 4, KB = t & 15;
    const float* row = trans + n * NTAGS;
    int wq = KB >> 1, h = KB & 1;
    float v[32]; float mx = -3.0e38f;
    #pragma unroll
    for (int k = 0; k < 32; ++k) {
        int p = wq*64 + (k & 3)*16 + h*8 + (k >> 2);
        v[k] = row[p]; mx = fmaxf(mx, v[k]);
    }
    int e = (int)floorf(mx * L2E - 2.90689059f);     // blockmax -> (3.75, 7.5]
    int byt = e + 127; byt = byt < 0 ? 0 : (byt > 254 ? 254 : byt);
    float eeff = (float)(byt - 127);
    uint32_t out[6] = {0u,0u,0u,0u,0u,0u};
    #pragma unroll
    for (int k = 0; k < 32; ++k) {
        float q = exp2f(v[k] * L2E - eeff);          // in [0, 7.5]
        int code;
        if      (q < 2.0f) code = (int)(q * 8.0f + 0.5f);
        else if (q < 4.0f) code = 16 + (int)((q - 2.0f) * 4.0f + 0.5f);
        else               code = 24 + (int)((q - 4.0f) * 2.0f + 0.5f);
        code = code > 31 ? 31 : code;
        int bp = 6*k, d = bp >> 5, off = bp & 31;
        out[d] |= (uint32_t)code << off;
        if (off > 26) out[d+1] |= (uint32_t)code >> (32 - off);
    }
    uint32_t* E6 = (uint32_t*)ws;
    int base = (n*16 + KB) * 6;
    #pragma unroll
    for (int d = 0; d < 6; ++d) E6[base + d] = out[d];
    ws[WS_SC + n*16 + (KB & 3)*4 + (KB >> 2)] = (uint8_t)byt;
}

// ---------------- main: 8 WGs x 16 batches, 512 threads (8 waves, 2/SIMD) ----------------
__global__ __launch_bounds__(512, 2) void crf_main_k(
    const float* __restrict__ inp, const float* __restrict__ trans,
    const uint8_t* __restrict__ ws, float* __restrict__ part)
{
    __shared__ uint8_t aqb[2*8192];
    __shared__ int     mxp[2*16];
    __shared__ float   mxb[16*8];
    __shared__ float   ssum[16*8];
    __shared__ float   Gb[16];

    const int tid = threadIdx.x;
    const int w = tid >> 6, l = tid & 63, c = l & 15, g = l >> 4;
    const int wg = blockIdx.x;
    const int b0 = g * 4;
    const int SCA = 0x78787878;   // constant A-scale: e8m0 120 = 2^-7, all blocks

    // ---- persistent B fragments: plain vector loads ----
    v8i Bf[16];
    int esc[4];
    #pragma unroll
    for (int i = 0; i < 4; ++i) {
        const int n = (w*4 + i)*16 + c;
        esc[i] = *(const int*)(ws + WS_SC + n*16 + g*4);
        #pragma unroll
        for (int kk = 0; kk < 4; ++kk) {
            const uint2* p2 = (const uint2*)((const uint32_t*)ws + (n*16 + kk*4 + g)*6);
            uint2 d0 = p2[0], d1 = p2[1], d2 = p2[2];
            v8i bv;
            bv[0]=(int)d0.x; bv[1]=(int)d0.y; bv[2]=(int)d1.x;
            bv[3]=(int)d1.y; bv[4]=(int)d2.x; bv[5]=(int)d2.y;
            bv[6]=0; bv[7]=0;
            Bf[i*4 + kk] = bv;
        }
    }
    // initial pin (prevents sink/remat of the loads)
    #pragma unroll
    for (int i = 0; i < 16; ++i) asm volatile("" : "+v"(Bf[i]));
    #pragma unroll
    for (int i = 0; i < 4; ++i)  asm volatile("" : "+v"(esc[i]));

    const float* ep[4];
    #pragma unroll
    for (int j = 0; j < 4; ++j)
        ep[j] = inp + (size_t)(wg*16 + b0 + j) * (SEQ*NTAGS) + w*64 + c;   // row 0

    // hoisted quant-store indices (loop-invariant; only buffer parity alternates)
    int aqoff[4];
    #pragma unroll
    for (int j = 0; j < 4; ++j) {
        int bb = b0 + j;
        aqoff[j] = bb*128 + (((w*4 + (c>>2)) ^ (bb & 7)) << 2) + (c & 3);
    }

    // ---- init: alpha_1[n] = inp[b,0,n] + trans[n,STAG]; exact max; fp8 store (fold 0) ----
    float vv[4][4];
    {
        float tr[4];
        #pragma unroll
        for (int i = 0; i < 4; ++i) tr[i] = trans[(w*64 + i*16 + c)*NTAGS + STAG];
        #pragma unroll
        for (int j = 0; j < 4; ++j) {
            #pragma unroll
            for (int i = 0; i < 4; ++i)
                vv[j][i] = ep[j][i*16] + tr[i];
        }
    }
    float Mj[4];
    #pragma unroll
    for (int j = 0; j < 4; ++j) {
        float m = fmaxf(fmaxf(vv[j][0], vv[j][1]), fmaxf(vv[j][2], vv[j][3]));
        #pragma unroll
        for (int msk = 1; msk <= 8; msk <<= 1) m = fmaxf(m, __shfl_xor(m, msk, 64));
        if (c == 0) mxb[(b0 + j)*8 + w] = m;
    }
    __syncthreads();
    float G[4];
    #pragma unroll
    for (int j = 0; j < 4; ++j) {
        float m = -3.0e38f;
        #pragma unroll
        for (int k = 0; k < 8; ++k) m = fmaxf(m, mxb[(b0 + j)*8 + k]);
        Mj[j] = m;
        G[j] = m * L2E;
    }
    {
        uint32_t* AQ = (uint32_t*)(aqb + 8192);   // buffer 1 (s=1 reads cur=1)
        #pragma unroll
        for (int j = 0; j < 4; ++j) {
            float q0 = fexp2((vv[j][0] - Mj[j]) * L2E + 7.0f);
            float q1 = fexp2((vv[j][1] - Mj[j]) * L2E + 7.0f);
            float q2 = fexp2((vv[j][2] - Mj[j]) * L2E + 7.0f);
            float q3 = fexp2((vv[j][3] - Mj[j]) * L2E + 7.0f);
            int t_ = __builtin_amdgcn_cvt_pk_fp8_f32(q0, q1, 0, false);
            t_ = __builtin_amdgcn_cvt_pk_fp8_f32(q2, q3, t_, true);
            AQ[aqoff[j]] = (uint32_t)t_;
        }
    }
    if (w == 0 && c == 0) { int4 z; z.x=0; z.y=0; z.z=0; z.w=0; *(int4*)&mxp[16 + g*4] = z; }

    // prologue: advance ep to row 1, prefetch raw em(s=1)
    float emn[4][4];
    #pragma unroll
    for (int j = 0; j < 4; ++j) ep[j] += NTAGS;
    #pragma unroll
    for (int j = 0; j < 4; ++j) {
        #pragma unroll
        for (int i = 0; i < 4; ++i) emn[j][i] = ep[j][i*16];
    }
    __syncthreads();

    int aoffA[8];
    #pragma unroll
    for (int kk = 0; kk < 4; ++kk) {
        aoffA[2*kk]   = c*32 + ((kk*8 + g*2)     ^ (c & 7));
        aoffA[2*kk+1] = c*32 + ((kk*8 + g*2 + 1) ^ (c & 7));
    }

#define MFMA_K(KK) do { \
    v8i A_; \
    *(int4*)&A_       = aq4[aoffA[2*(KK)]]; \
    *(((int4*)&A_)+1) = aq4[aoffA[2*(KK)+1]]; \
    D[0] = __builtin_amdgcn_mfma_scale_f32_16x16x128_f8f6f4(A_, Bf[0*4+(KK)], D[0], 0, 2, (KK), SCA, (KK), esc[0]); \
    D[1] = __builtin_amdgcn_mfma_scale_f32_16x16x128_f8f6f4(A_, Bf[1*4+(KK)], D[1], 0, 2, (KK), SCA, (KK), esc[1]); \
    D[2] = __builtin_amdgcn_mfma_scale_f32_16x16x128_f8f6f4(A_, Bf[2*4+(KK)], D[2], 0, 2, (KK), SCA, (KK), esc[2]); \
    D[3] = __builtin_amdgcn_mfma_scale_f32_16x16x128_f8f6f4(A_, Bf[3*4+(KK)], D[3], 0, 2, (KK), SCA, (KK), esc[3]); \
} while (0)

    for (int s = 1; s < SEQ; ++s) {
        const int cur = s & 1, nxt = cur ^ 1;

        // Re-pin B fragments to VGPRs EVERY iteration: without this the
        // allocator parks Bf in AGPRs and emits 8 accvgpr_read per MFMA
        // (~128 VALU copies/thread/step -- the R7 VALU flood).
        asm volatile("" : "+v"(Bf[0]), "+v"(Bf[1]), "+v"(Bf[2]), "+v"(Bf[3]),
                          "+v"(Bf[4]), "+v"(Bf[5]), "+v"(Bf[6]), "+v"(Bf[7]),
                          "+v"(Bf[8]), "+v"(Bf[9]), "+v"(Bf[10]), "+v"(Bf[11]),
                          "+v"(Bf[12]), "+v"(Bf[13]), "+v"(Bf[14]), "+v"(Bf[15]));

        // stale per-batch fold: Rj = posted-max + MARGIN; dm folds 2^(7-Rj) into emission
        int4 Pv = *(const int4*)&mxp[cur*16 + g*4];
        int Rj[4]; float dmj[4];
        #pragma unroll
        for (int j = 0; j < 4; ++j) {
            Rj[j] = ((const int*)&Pv)[j] + MARGIN;
            dmj[j] = (float)(7 - Rj[j]);
        }

        // folded emission factors (raw em prefetched last step, already resident)
        float emx[4][4];
        #pragma unroll
        for (int j = 0; j < 4; ++j) {
            #pragma unroll
            for (int i = 0; i < 4; ++i)
                emx[j][i] = fexp2(fmaf(emn[j][i], L2E, dmj[j]));
        }
        // prefetch raw em for NEXT step (survives the raw barrier; drains at next use)
        if (s < SEQ - 1) {
            #pragma unroll
            for (int j = 0; j < 4; ++j) ep[j] += NTAGS;
            #pragma unroll
            for (int j = 0; j < 4; ++j) {
                #pragma unroll
                for (int i = 0; i < 4; ++i) emn[j][i] = ep[j][i*16];
            }
        }

        const int4* aq4 = (const int4*)(aqb + cur*8192);

        v4f D[4];
        #pragma unroll
        for (int i = 0; i < 4; ++i) { D[i][0]=0.f; D[i][1]=0.f; D[i][2]=0.f; D[i][3]=0.f; }
        __builtin_amdgcn_s_setprio(1);
        MFMA_K(0); MFMA_K(1); MFMA_K(2); MFMA_K(3);
        __builtin_amdgcn_s_setprio(0);

        if (s < SEQ - 1) {
            #pragma unroll
            for (int j = 0; j < 4; ++j) G[j] += (float)Rj[j];

            // quantize (fold already in emx); fminf(448) REQUIRED (fp8 cvt overflow = NaN)
            float vq[4][4];
            #pragma unroll
            for (int j = 0; j < 4; ++j) {
                #pragma unroll
                for (int i = 0; i < 4; ++i)
                    vq[j][i] = fminf(D[i][j] * emx[j][i], 448.0f);
            }
            uint32_t* AQ = (uint32_t*)(aqb + nxt*8192);
            #pragma unroll
            for (int j = 0; j < 4; ++j) {
                int t_ = __builtin_amdgcn_cvt_pk_fp8_f32(vq[j][0], vq[j][1], 0, false);
                t_ = __builtin_amdgcn_cvt_pk_fp8_f32(vq[j][2], vq[j][3], t_, true);
                AQ[aqoff[j]] = (uint32_t)t_;
            }
            if (w == 0) {   // wave-uniform: stale-max post only on wave 0 (64-n sample)
                int4 post;
                #pragma unroll
                for (int j = 0; j < 4; ++j) {
                    float bm = fmaxf(fmaxf(vq[j][0], vq[j][1]), fmaxf(vq[j][2], vq[j][3]));
                    bm = DPPMAX(bm, 0xB1); bm = DPPMAX(bm, 0x4E);
                    bm = DPPMAX(bm, 0x141); bm = DPPMAX(bm, 0x140);
                    int be = (int)((__float_as_uint(bm) >> 23) & 255u) - 127;
                    be = be < -30 ? -30 : be;
                    ((int*)&post)[j] = be - 7;   // == exp(unfolded v-max) - Rj
                }
                if (c == 0) *(int4*)&mxp[nxt*16 + g*4] = post;
            }
            STEP_SYNC();
        } else {
            // ---- final: loss_b = LN2*(G + max_x + log2 sum 2^(x - max)); emn holds raw em(511) ----
            float ts[4];
            #pragma unroll
            for (int i = 0; i < 4; ++i) ts[i] = trans[PTAG*NTAGS + w*64 + i*16 + c];
            float x[4][4];
            #pragma unroll
            for (int j = 0; j < 4; ++j) {
                #pragma unroll
                for (int i = 0; i < 4; ++i)
                    x[j][i] = __log2f(D[i][j]) + (emn[j][i] + ts[i]) * L2E;
            }
            #pragma unroll
            for (int j = 0; j < 4; ++j) {
                float m = fmaxf(fmaxf(x[j][0], x[j][1]), fmaxf(x[j][2], x[j][3]));
                #pragma unroll
                for (int msk = 1; msk <= 8; msk <<= 1) m = fmaxf(m, __shfl_xor(m, msk, 64));
                if (c == 0) mxb[(b0 + j)*8 + w] = m;
            }
            if (w == 0 && c == 0) {
                #pragma unroll
                for (int j = 0; j < 4; ++j) Gb[b0 + j] = G[j];
            }
            __syncthreads();
            #pragma unroll
            for (int j = 0; j < 4; ++j) {
                float XM = -3.0e38f;
                #pragma unroll
                for (int k = 0; k < 8; ++k) XM = fmaxf(XM, mxb[(b0 + j)*8 + k]);
                float sj = fexp2(x[j][0] - XM) + fexp2(x[j][1] - XM)
                         + fexp2(x[j][2] - XM) + fexp2(x[j][3] - XM);
                #pragma unroll
                for (int msk = 1; msk <= 8; msk <<= 1) sj += __shfl_xor(sj, msk, 64);
                if (c == 0) ssum[(b0 + j)*8 + w] = sj;
            }
            __syncthreads();
            if (tid < 16) {
                float S = 0.f, XM = -3.0e38f;
                #pragma unroll
                for (int k = 0; k < 8; ++k) { S += ssum[tid*8 + k]; XM = fmaxf(XM, mxb[tid*8 + k]); }
                part[wg*16 + tid] = LN2 * (Gb[tid] + XM + __log2f(S));
            }
        }
    }
#undef MFMA_K
}

__global__ void crf_final_k(const float* __restrict__ part, float* __restrict__ out)
{
    int t = threadIdx.x;  // 64
    float vsum = part[t] + part[t + 64];
    #pragma unroll
    for (int off = 32; off; off >>= 1) vsum += __shfl_down(vsum, off, 64);
    if (t == 0) out[0] = vsum;
}

extern "C" void kernel_launch(void* const* d_in, const int* in_sizes, int n_in,
                              void* d_out, int out_size, void* d_ws, size_t ws_size,
                              hipStream_t stream)
{
    (void)in_sizes; (void)n_in; (void)out_size; (void)ws_size;
    const float* inp   = (const float*)d_in[0];
    // d_in[1] = tags: unused (partition function only)
    const float* trans = (const float*)d_in[2];
    uint8_t* ws = (uint8_t*)d_ws;
    float* part = (float*)(ws + WS_PART);

    crf_setup_k<<<64, 128, 0, stream>>>(trans, ws);
    crf_main_k<<<8, 512, 0, stream>>>(inp, trans, ws, part);
    crf_final_k<<<1, 64, 0, stream>>>(part, (float*)d_out);
}